// Round 2
// baseline (5871.634 us; speedup 1.0000x reference)
//
#include <hip/hip_runtime.h>

typedef __attribute__((ext_vector_type(8))) short bf16x8;
typedef __attribute__((ext_vector_type(4))) float f32x4;
typedef __attribute__((ext_vector_type(2))) float f32x2;

#define DEV static __device__ __forceinline__

DEV unsigned short f2bf(float f) {
    union { float f; unsigned u; } a; a.f = f;
    unsigned r = a.u + 0x7FFFu + ((a.u >> 16) & 1u);
    return (unsigned short)(r >> 16);
}
DEV float bfl(unsigned u) { union { unsigned u; float f; } a; a.u = u << 16; return a.f; }
DEV float bfh(unsigned u) { union { unsigned u; float f; } a; a.u = u & 0xFFFF0000u; return a.f; }

// ---------------------------------------------------------------- weight prep
// Btw layout: plane p, Bt[p][c][k] = W[k][c], bf16.  p=0: w_in2, p=1: w_seg2,
// p in [2,62): iter i=(p-2)/15, t=(p-2)%15 (0=ctr,1..6=pre,7..12=suc,13=left,14=right),
// p in [62,66): ctr2_w[i].
__global__ void wprep(const float* __restrict__ w_in2, const float* __restrict__ w_seg2,
                      const float* __restrict__ ctr_w, const float* __restrict__ pre_w,
                      const float* __restrict__ suc_w, const float* __restrict__ left_w,
                      const float* __restrict__ right_w, const float* __restrict__ ctr2_w,
                      unsigned short* __restrict__ Btw) {
    int idx = blockIdx.x * 256 + threadIdx.x;
    if (idx >= 66 * 16384) return;
    int p = idx >> 14, within = idx & 16383;
    int c = within >> 7, k = within & 127;
    const float* src;
    if (p == 0) src = w_in2;
    else if (p == 1) src = w_seg2;
    else if (p < 62) {
        int pi = p - 2; int i = pi / 15, t = pi % 15;
        if (t == 0) src = ctr_w + i * 16384;
        else if (t < 7) src = pre_w + (i * 6 + (t - 1)) * 16384;
        else if (t < 13) src = suc_w + (i * 6 + (t - 7)) * 16384;
        else if (t == 13) src = left_w + i * 16384;
        else src = right_w + i * 16384;
    } else src = ctr2_w + (p - 62) * 16384;
    Btw[idx] = f2bf(src[k * 128 + c]);
}

// ---------------------------------------------------------------- CSR build
__global__ void edge_count(const int* __restrict__ pre_u, const int* __restrict__ suc_u,
                           const int* __restrict__ left_u, const int* __restrict__ right_u,
                           int E, int E2, int Mtot, int* __restrict__ cnt) {
    int e = blockIdx.x * 256 + threadIdx.x;
    if (e >= Mtot) return;
    int u;
    if (e < 12 * E) {
        int t = e / E, off = e - t * E;
        u = (t < 6) ? pre_u[t * E + off] : suc_u[(t - 6) * E + off];
    } else {
        int e2 = e - 12 * E;
        u = (e2 < E2) ? left_u[e2] : right_u[e2 - E2];
    }
    atomicAdd(&cnt[u], 1);
}

__global__ void scanA(const int* __restrict__ cnt, int N, int* __restrict__ rowptr,
                      int* __restrict__ bsum) {
    __shared__ int lds[256];
    int tid = threadIdx.x;
    int base = blockIdx.x * 2048 + tid * 8;
    int v[8]; int s = 0;
#pragma unroll
    for (int j = 0; j < 8; ++j) { int i = base + j; v[j] = (i < N) ? cnt[i] : 0; s += v[j]; }
    lds[tid] = s; __syncthreads();
    for (int d = 1; d < 256; d <<= 1) {
        int t2 = (tid >= d) ? lds[tid - d] : 0;
        __syncthreads();
        lds[tid] += t2;
        __syncthreads();
    }
    int excl = lds[tid] - s;
    if (tid == 255) bsum[blockIdx.x] = lds[255];
    int run = excl;
#pragma unroll
    for (int j = 0; j < 8; ++j) { int i = base + j; if (i < N) rowptr[i] = run; run += v[j]; }
}

__global__ void scanB(int* __restrict__ bsum, int nb, int* __restrict__ totalOut) {
    __shared__ int lds[128];
    int tid = threadIdx.x;
    int v = (tid < nb) ? bsum[tid] : 0;
    lds[tid] = v; __syncthreads();
    for (int d = 1; d < 128; d <<= 1) {
        int t2 = (tid >= d) ? lds[tid - d] : 0;
        __syncthreads();
        lds[tid] += t2;
        __syncthreads();
    }
    if (tid < nb) bsum[tid] = lds[tid] - v;
    if (tid == 127) *totalOut = lds[127];
}

__global__ void scanC(int* __restrict__ rowptr, const int* __restrict__ bsum, int N) {
    int i = blockIdx.x * 256 + threadIdx.x;
    if (i < N) rowptr[i] += bsum[i >> 11];
}

__global__ void edge_fill(const int* __restrict__ pre_u, const int* __restrict__ pre_v,
                          const int* __restrict__ suc_u, const int* __restrict__ suc_v,
                          const int* __restrict__ left_u, const int* __restrict__ left_v,
                          const int* __restrict__ right_u, const int* __restrict__ right_v,
                          int E, int E2, int Mtot, const int* __restrict__ rowptr,
                          int* __restrict__ cur, int* __restrict__ edata) {
    int e = blockIdx.x * 256 + threadIdx.x;
    if (e >= Mtot) return;
    int u, v, t;
    if (e < 12 * E) {
        int s = e / E, off = e - s * E;
        if (s < 6) { u = pre_u[s * E + off]; v = pre_v[s * E + off]; }
        else { u = suc_u[(s - 6) * E + off]; v = suc_v[(s - 6) * E + off]; }
        t = 1 + s;
    } else {
        int e2 = e - 12 * E;
        if (e2 < E2) { u = left_u[e2]; v = left_v[e2]; t = 13; }
        else { u = right_u[e2 - E2]; v = right_v[e2 - E2]; t = 14; }
    }
    int pos = atomicAdd(&cur[u], 1);
    edata[rowptr[u] + pos] = (t << 18) | v;
}

// ---------------------------------------------------------------- encoders (first linear+relu)
__global__ void enc(const float* __restrict__ ctrs, const float* __restrict__ feats,
                    const float* __restrict__ w_in1, const float* __restrict__ b_in1,
                    const float* __restrict__ w_seg1, const float* __restrict__ b_seg1,
                    unsigned short* __restrict__ h_in, unsigned short* __restrict__ h_seg, int N) {
    int idx = blockIdx.x * 256 + threadIdx.x;
    if (idx >= N * 128) return;
    int n = idx >> 7, c = idx & 127;
    float x0 = ctrs[2 * n], x1 = ctrs[2 * n + 1];
    float h = fmaxf(x0 * w_in1[c] + x1 * w_in1[128 + c] + b_in1[c], 0.f);
    h_in[idx] = f2bf(h);
    x0 = feats[2 * n]; x1 = feats[2 * n + 1];
    h = fmaxf(x0 * w_seg1[c] + x1 * w_seg1[128 + c] + b_seg1[c], 0.f);
    h_seg[idx] = f2bf(h);
}

// ---------------------------------------------------------------- GEMM (128-row tile, K=128)
// Swapped MFMA orientation: mfma(A=W^T frag, B=feat frag) so each lane's 4 acc
// regs are 4 CONSECUTIVE output columns -> coalesced stores + wave-local GN.
enum { MODE_X = 0, MODE_GN = 1, MODE_GNADD = 2 };

template <int MODE>
__global__ __launch_bounds__(256, 2) void gemm128(
    const unsigned short* __restrict__ A,   // [M][128] bf16
    const unsigned short* __restrict__ Bt,  // [nt][128][128] bf16, Bt[t][c][k]
    int nt, int M,
    unsigned short* __restrict__ Xout,      // MODE_X: [nt][M][128] bf16
    const float* __restrict__ resf,         // MODE_GNADD
    float* __restrict__ outf,               // MODE_GN / MODE_GNADD
    unsigned short* __restrict__ outb,      // MODE_GNADD
    const float* __restrict__ gw, const float* __restrict__ gb) {
    __shared__ char Asm[32768];
    __shared__ char Bsm[32768];
    const int tid = threadIdx.x;
    const int wv = tid >> 6, ln = tid & 63;
    const int q = ln >> 4, r = ln & 15;
    const int m0 = blockIdx.x * 128;

    // stage A tile once: 128 rows x 16 int4-chunks, XOR-swizzled (byte ^= (row&7)<<4)
#pragma unroll
    for (int s = 0; s < 8; ++s) {
        int f = s * 256 + tid;
        int row = f >> 4, ck = f & 15;
        int grow = m0 + row; if (grow >= M) grow = M - 1;
        int4 v = *(const int4*)(A + (size_t)grow * 128 + ck * 8);
        *(int4*)(Asm + row * 256 + ((ck * 16) ^ ((row & 7) << 4))) = v;
    }

    for (int t = 0; t < nt; ++t) {
        __syncthreads();
        const unsigned short* Bp = Bt + (size_t)t * 16384;
#pragma unroll
        for (int s = 0; s < 8; ++s) {
            int f = s * 256 + tid;
            int c = f >> 4, ck = f & 15;
            int4 v = *(const int4*)(Bp + c * 128 + ck * 8);
            *(int4*)(Bsm + c * 256 + ((ck * 16) ^ ((c & 7) << 4))) = v;
        }
        __syncthreads();

        f32x4 acc[2][8];
#pragma unroll
        for (int fj = 0; fj < 2; ++fj)
#pragma unroll
            for (int ci = 0; ci < 8; ++ci) acc[fj][ci] = (f32x4)(0.f);

#pragma unroll
        for (int k0 = 0; k0 < 128; k0 += 32) {
            int kb = k0 * 2 + q * 16;
            bf16x8 wf[8], ff[2];
#pragma unroll
            for (int ci = 0; ci < 8; ++ci) {
                int c = ci * 16 + r;
                wf[ci] = *(const bf16x8*)(Bsm + c * 256 + (kb ^ ((c & 7) << 4)));
            }
#pragma unroll
            for (int fj = 0; fj < 2; ++fj) {
                int row = wv * 32 + fj * 16 + r;
                ff[fj] = *(const bf16x8*)(Asm + row * 256 + (kb ^ ((row & 7) << 4)));
            }
#pragma unroll
            for (int fj = 0; fj < 2; ++fj)
#pragma unroll
                for (int ci = 0; ci < 8; ++ci)
                    acc[fj][ci] = __builtin_amdgcn_mfma_f32_16x16x32_bf16(wf[ci], ff[fj], acc[fj][ci], 0, 0, 0);
        }

        if (MODE == MODE_X) {
#pragma unroll
            for (int fj = 0; fj < 2; ++fj) {
                int row = m0 + wv * 32 + fj * 16 + r;
                if (row < M) {
                    unsigned short* dst = Xout + (size_t)t * (size_t)M * 128 + (size_t)row * 128;
#pragma unroll
                    for (int ci = 0; ci < 8; ++ci) {
                        int col = ci * 16 + q * 4;
                        f32x4 a = acc[fj][ci];
                        unsigned lo = (unsigned)f2bf(a[0]) | ((unsigned)f2bf(a[1]) << 16);
                        unsigned hi = (unsigned)f2bf(a[2]) | ((unsigned)f2bf(a[3]) << 16);
                        int2 pk; pk.x = (int)lo; pk.y = (int)hi;
                        *(int2*)(dst + col) = pk;
                    }
                }
            }
        } else {
#pragma unroll
            for (int fj = 0; fj < 2; ++fj) {
                float s = 0.f;
#pragma unroll
                for (int ci = 0; ci < 8; ++ci) {
                    f32x4 a = acc[fj][ci];
                    s += a[0] + a[1] + a[2] + a[3];
                }
                s += __shfl_xor(s, 16); s += __shfl_xor(s, 32);
                float mean = s * (1.f / 128.f);
                float vs = 0.f;
#pragma unroll
                for (int ci = 0; ci < 8; ++ci) {
                    f32x4 a = acc[fj][ci];
#pragma unroll
                    for (int j = 0; j < 4; ++j) { float d = a[j] - mean; vs += d * d; }
                }
                vs += __shfl_xor(vs, 16); vs += __shfl_xor(vs, 32);
                float inv = rsqrtf(vs * (1.f / 128.f) + 1e-5f);
                int row = m0 + wv * 32 + fj * 16 + r;
                if (row < M) {
#pragma unroll
                    for (int ci = 0; ci < 8; ++ci) {
                        int col = ci * 16 + q * 4;
                        f32x4 a = acc[fj][ci];
                        float4 gv = *(const float4*)(gw + col);
                        float4 bv = *(const float4*)(gb + col);
                        float y0 = (a[0] - mean) * inv * gv.x + bv.x;
                        float y1 = (a[1] - mean) * inv * gv.y + bv.y;
                        float y2 = (a[2] - mean) * inv * gv.z + bv.z;
                        float y3 = (a[3] - mean) * inv * gv.w + bv.w;
                        if (MODE == MODE_GNADD) {
                            float4 rv = *(const float4*)(resf + (size_t)row * 128 + col);
                            y0 = fmaxf(y0 + rv.x, 0.f);
                            y1 = fmaxf(y1 + rv.y, 0.f);
                            y2 = fmaxf(y2 + rv.z, 0.f);
                            y3 = fmaxf(y3 + rv.w, 0.f);
                            float4 o; o.x = y0; o.y = y1; o.z = y2; o.w = y3;
                            *(float4*)(outf + (size_t)row * 128 + col) = o;
                            unsigned lo = (unsigned)f2bf(y0) | ((unsigned)f2bf(y1) << 16);
                            unsigned hi = (unsigned)f2bf(y2) | ((unsigned)f2bf(y3) << 16);
                            int2 pk; pk.x = (int)lo; pk.y = (int)hi;
                            *(int2*)(outb + (size_t)row * 128 + col) = pk;
                        } else {
                            float4 o; o.x = y0; o.y = y1; o.z = y2; o.w = y3;
                            *(float4*)(outf + (size_t)row * 128 + col) = o;
                        }
                    }
                }
            }
        }
    }
}

// ---------------------------------------------------------------- gather + GN + ReLU
// One wave per node u: acc(128 cols, 2 f32/lane) = X_ctr[u] (+temp) + sum over
// incoming edges of X_t[v]; last chunk applies GroupNorm+ReLU -> feat1b bf16.
template <int FIRST, int LAST>
__global__ __launch_bounds__(256) void gather_gn(
    const unsigned* __restrict__ Xu, int ts, int te, int Nn,
    const int* __restrict__ rowptr, const int* __restrict__ edata,
    float* __restrict__ temp, unsigned* __restrict__ feat1b,
    const float* __restrict__ gw, const float* __restrict__ gb) {
    const int ln = threadIdx.x & 63;
    const int u = blockIdx.x * 4 + (threadIdx.x >> 6);
    if (u >= Nn) return;
    float a0, a1;
    if (FIRST) {
        unsigned p = Xu[(size_t)u * 64 + ln];  // plane 0 = ctr
        a0 = bfl(p); a1 = bfh(p);
    } else {
        f32x2 v = *(const f32x2*)(temp + (size_t)u * 128 + ln * 2);
        a0 = v.x; a1 = v.y;
    }
    const int tlo = FIRST ? 1 : ts;
    const int e1 = rowptr[u + 1];
    for (int e = rowptr[u]; e < e1; ++e) {
        int val = edata[e];
        int t = val >> 18;
        if (t < tlo || t >= te) continue;
        int v = val & 0x3FFFF;
        unsigned p = Xu[((size_t)(t - ts) * Nn + (size_t)v) * 64 + ln];
        a0 += bfl(p); a1 += bfh(p);
    }
    if (LAST) {
        float s = a0 + a1;
#pragma unroll
        for (int d = 1; d < 64; d <<= 1) s += __shfl_xor(s, d);
        float mean = s * (1.f / 128.f);
        float d0 = a0 - mean, d1 = a1 - mean;
        float vs = d0 * d0 + d1 * d1;
#pragma unroll
        for (int d = 1; d < 64; d <<= 1) vs += __shfl_xor(vs, d);
        float inv = rsqrtf(vs * (1.f / 128.f) + 1e-5f);
        int c = ln * 2;
        float y0 = fmaxf(d0 * inv * gw[c] + gb[c], 0.f);
        float y1 = fmaxf(d1 * inv * gw[c + 1] + gb[c + 1], 0.f);
        feat1b[(size_t)u * 64 + ln] = (unsigned)f2bf(y0) | ((unsigned)f2bf(y1) << 16);
    } else {
        f32x2 v; v.x = a0; v.y = a1;
        *(f32x2*)(temp + (size_t)u * 128 + ln * 2) = v;
    }
}

// ---------------------------------------------------------------- launch
extern "C" void kernel_launch(void* const* d_in, const int* in_sizes, int n_in,
                              void* d_out, int out_size, void* d_ws, size_t ws_size,
                              hipStream_t stream) {
    const float* ctrs = (const float*)d_in[0];
    const float* feats = (const float*)d_in[1];
    const float* w_in1 = (const float*)d_in[2];
    const float* b_in1 = (const float*)d_in[3];
    const float* w_in2 = (const float*)d_in[4];
    const float* g_in = (const float*)d_in[5];
    const float* be_in = (const float*)d_in[6];
    const float* w_seg1 = (const float*)d_in[7];
    const float* b_seg1 = (const float*)d_in[8];
    const float* w_seg2 = (const float*)d_in[9];
    const float* g_seg = (const float*)d_in[10];
    const float* be_seg = (const float*)d_in[11];
    const float* ctr_w = (const float*)d_in[12];
    const float* pre_w = (const float*)d_in[13];
    const float* suc_w = (const float*)d_in[14];
    const float* left_w = (const float*)d_in[15];
    const float* right_w = (const float*)d_in[16];
    const float* norm_g = (const float*)d_in[17];
    const float* norm_b = (const float*)d_in[18];
    const float* ctr2_w = (const float*)d_in[19];
    const float* ctr2_g = (const float*)d_in[20];
    const float* ctr2_b = (const float*)d_in[21];
    const int* pre_u = (const int*)d_in[22];
    const int* pre_v = (const int*)d_in[23];
    const int* suc_u = (const int*)d_in[24];
    const int* suc_v = (const int*)d_in[25];
    const int* left_u = (const int*)d_in[26];
    const int* left_v = (const int*)d_in[27];
    const int* right_u = (const int*)d_in[28];
    const int* right_v = (const int*)d_in[29];

    const int N = in_sizes[0] / 2;
    const int E = in_sizes[22] / 6;
    const int E2 = in_sizes[26];
    const int Mtot = 12 * E + 2 * E2;

    char* ws = (char*)d_ws;
    size_t off = 0;
    auto alloc = [&](size_t b) { void* p = ws + off; off += (b + 255) & ~(size_t)255; return p; };

    unsigned short* Btw = (unsigned short*)alloc((size_t)66 * 16384 * 2);
    unsigned short* featb = (unsigned short*)alloc((size_t)N * 128 * 2);
    unsigned short* feat1b = (unsigned short*)alloc((size_t)N * 128 * 2);
    float* tempP = (float*)alloc((size_t)N * 128 * 4);
    int* rowptr = (int*)alloc((size_t)(N + 1) * 4);
    int* cnt = (int*)alloc((size_t)N * 4);
    int* bsum = (int*)alloc(1024);
    int* edata = (int*)alloc((size_t)Mtot * 4);
    size_t planeB = (size_t)N * 128 * 2;
    size_t rem = ws_size > off ? ws_size - off : 0;
    int navail = (int)(rem / planeB);
    if (navail > 15) navail = 15;
    if (navail < 1) navail = 1;
    unsigned short* X = (unsigned short*)(ws + off);

    float* featf = (float*)d_out;

    // weights -> bf16 transposed planes
    wprep<<<dim3((66 * 16384 + 255) / 256), dim3(256), 0, stream>>>(
        w_in2, w_seg2, ctr_w, pre_w, suc_w, left_w, right_w, ctr2_w, Btw);

    // CSR build (amortized over 4 iterations)
    hipMemsetAsync(cnt, 0, (size_t)N * 4, stream);
    edge_count<<<dim3((Mtot + 255) / 256), dim3(256), 0, stream>>>(
        pre_u, suc_u, left_u, right_u, E, E2, Mtot, cnt);
    int nb = (N + 2047) / 2048;
    scanA<<<dim3(nb), dim3(256), 0, stream>>>(cnt, N, rowptr, bsum);
    scanB<<<dim3(1), dim3(128), 0, stream>>>(bsum, nb, rowptr + N);
    scanC<<<dim3((N + 255) / 256), dim3(256), 0, stream>>>(rowptr, bsum, N);
    hipMemsetAsync(cnt, 0, (size_t)N * 4, stream);
    edge_fill<<<dim3((Mtot + 255) / 256), dim3(256), 0, stream>>>(
        pre_u, pre_v, suc_u, suc_v, left_u, left_v, right_u, right_v,
        E, E2, Mtot, rowptr, cnt, edata);

    // encoders: h_in -> feat1b, h_seg -> featb (reused as scratch here)
    enc<<<dim3((N * 128 + 255) / 256), dim3(256), 0, stream>>>(
        ctrs, feats, w_in1, b_in1, w_seg1, b_seg1, feat1b, featb, N);
    const int gblk = (N + 127) / 128;
    gemm128<MODE_GN><<<dim3(gblk), dim3(256), 0, stream>>>(
        feat1b, Btw + 0, 1, N, (unsigned short*)nullptr,
        (const float*)nullptr, tempP, (unsigned short*)nullptr, g_in, be_in);
    gemm128<MODE_GNADD><<<dim3(gblk), dim3(256), 0, stream>>>(
        featb, Btw + 16384, 1, N, (unsigned short*)nullptr,
        tempP, featf, featb, g_seg, be_seg);

    // fuse iterations
    for (int i = 0; i < 4; ++i) {
        for (int ts = 0; ts < 15; ts += navail) {
            int te = ts + navail; if (te > 15) te = 15;
            gemm128<MODE_X><<<dim3(gblk), dim3(256), 0, stream>>>(
                featb, Btw + (size_t)(2 + i * 15 + ts) * 16384, te - ts, N, X,
                (const float*)nullptr, (float*)nullptr, (unsigned short*)nullptr,
                (const float*)nullptr, (const float*)nullptr);
            dim3 ggrid((N + 3) / 4);
            int F = (ts == 0), L = (te == 15);
            if (F && L)
                gather_gn<1, 1><<<ggrid, dim3(256), 0, stream>>>(
                    (const unsigned*)X, ts, te, N, rowptr, edata, tempP,
                    (unsigned*)feat1b, norm_g + i * 128, norm_b + i * 128);
            else if (F)
                gather_gn<1, 0><<<ggrid, dim3(256), 0, stream>>>(
                    (const unsigned*)X, ts, te, N, rowptr, edata, tempP,
                    (unsigned*)feat1b, norm_g + i * 128, norm_b + i * 128);
            else if (L)
                gather_gn<0, 1><<<ggrid, dim3(256), 0, stream>>>(
                    (const unsigned*)X, ts, te, N, rowptr, edata, tempP,
                    (unsigned*)feat1b, norm_g + i * 128, norm_b + i * 128);
            else
                gather_gn<0, 0><<<ggrid, dim3(256), 0, stream>>>(
                    (const unsigned*)X, ts, te, N, rowptr, edata, tempP,
                    (unsigned*)feat1b, norm_g + i * 128, norm_b + i * 128);
        }
        gemm128<MODE_GNADD><<<dim3(gblk), dim3(256), 0, stream>>>(
            feat1b, Btw + (size_t)(62 + i) * 16384, 1, N, (unsigned short*)nullptr,
            featf, featf, featb, ctr2_g + i * 128, ctr2_b + i * 128);
    }
}

// Round 4
// 3384.948 us; speedup vs baseline: 1.7346x; 1.7346x over previous
//
#include <hip/hip_runtime.h>

typedef __attribute__((ext_vector_type(8))) short bf16x8;
typedef __attribute__((ext_vector_type(4))) float f32x4;

#define DEV static __device__ __forceinline__

DEV unsigned short f2bf(float f) {
    union { float f; unsigned u; } a; a.f = f;
    unsigned r = a.u + 0x7FFFu + ((a.u >> 16) & 1u);
    return (unsigned short)(r >> 16);
}
DEV float bfl(unsigned u) { union { unsigned u; float f; } a; a.u = u << 16; return a.f; }
DEV float bfh(unsigned u) { union { unsigned u; float f; } a; a.u = u & 0xFFFF0000u; return a.f; }

// ---------------------------------------------------------------- weight prep
// Btw plane p: Bt[p][c][k] = W[k][c] bf16. p=0 w_in2, p=1 w_seg2,
// p in [2,62): iter i=(p-2)/15, t=(p-2)%15 (0=ctr,1..6=pre,7..12=suc,13=left,14=right),
// p in [62,66): ctr2_w[i].
__global__ void wprep(const float* __restrict__ w_in2, const float* __restrict__ w_seg2,
                      const float* __restrict__ ctr_w, const float* __restrict__ pre_w,
                      const float* __restrict__ suc_w, const float* __restrict__ left_w,
                      const float* __restrict__ right_w, const float* __restrict__ ctr2_w,
                      unsigned short* __restrict__ Btw) {
    int idx = blockIdx.x * 256 + threadIdx.x;
    if (idx >= 66 * 16384) return;
    int p = idx >> 14, within = idx & 16383;
    int c = within >> 7, k = within & 127;
    const float* src;
    if (p == 0) src = w_in2;
    else if (p == 1) src = w_seg2;
    else if (p < 62) {
        int pi = p - 2; int i = pi / 15, t = pi % 15;
        if (t == 0) src = ctr_w + i * 16384;
        else if (t < 7) src = pre_w + (i * 6 + (t - 1)) * 16384;
        else if (t < 13) src = suc_w + (i * 6 + (t - 7)) * 16384;
        else if (t == 13) src = left_w + i * 16384;
        else src = right_w + i * 16384;
    } else src = ctr2_w + (p - 62) * 16384;
    Btw[idx] = f2bf(src[k * 128 + c]);
}

// ---------------------------------------------------------------- CSR build (per type-group)
DEV int edge_decode(int e, int E, int E2,
                    const int* pre_u, const int* pre_v, const int* suc_u, const int* suc_v,
                    const int* left_u, const int* left_v, const int* right_u, const int* right_v,
                    int* u, int* v) {
    if (e < 12 * E) {
        int s = e / E, off = e - s * E;
        if (s < 6) { *u = pre_u[s * E + off]; *v = pre_v[s * E + off]; }
        else { *u = suc_u[(s - 6) * E + off]; *v = suc_v[(s - 6) * E + off]; }
        return 1 + s;
    }
    int e2 = e - 12 * E;
    if (e2 < E2) { *u = left_u[e2]; *v = left_v[e2]; return 13; }
    *u = right_u[e2 - E2]; *v = right_v[e2 - E2]; return 14;
}

__global__ void edge_count_r(const int* __restrict__ pre_u, const int* __restrict__ pre_v,
                             const int* __restrict__ suc_u, const int* __restrict__ suc_v,
                             const int* __restrict__ left_u, const int* __restrict__ left_v,
                             const int* __restrict__ right_u, const int* __restrict__ right_v,
                             int E, int E2, int Mtot, int t0, int t1, int* __restrict__ cnt) {
    int e = blockIdx.x * 256 + threadIdx.x;
    if (e >= Mtot) return;
    int u, v;
    int t = edge_decode(e, E, E2, pre_u, pre_v, suc_u, suc_v, left_u, left_v, right_u, right_v, &u, &v);
    if (t < t0 || t >= t1) return;
    atomicAdd(&cnt[u], 1);
}

__global__ void edge_fill_r(const int* __restrict__ pre_u, const int* __restrict__ pre_v,
                            const int* __restrict__ suc_u, const int* __restrict__ suc_v,
                            const int* __restrict__ left_u, const int* __restrict__ left_v,
                            const int* __restrict__ right_u, const int* __restrict__ right_v,
                            int E, int E2, int Mtot, int t0, int t1,
                            const int* __restrict__ rowptr, int* __restrict__ cur,
                            int* __restrict__ edata) {
    int e = blockIdx.x * 256 + threadIdx.x;
    if (e >= Mtot) return;
    int u, v;
    int t = edge_decode(e, E, E2, pre_u, pre_v, suc_u, suc_v, left_u, left_v, right_u, right_v, &u, &v);
    if (t < t0 || t >= t1) return;
    int pos = atomicAdd(&cur[u], 1);
    edata[rowptr[u] + pos] = ((t - t0) << 18) | v;
}

__global__ void scanA(const int* __restrict__ cnt, int N, int* __restrict__ rowptr,
                      int* __restrict__ bsum) {
    __shared__ int lds[256];
    int tid = threadIdx.x;
    int base = blockIdx.x * 2048 + tid * 8;
    int v[8]; int s = 0;
#pragma unroll
    for (int j = 0; j < 8; ++j) { int i = base + j; v[j] = (i < N) ? cnt[i] : 0; s += v[j]; }
    lds[tid] = s; __syncthreads();
    for (int d = 1; d < 256; d <<= 1) {
        int t2 = (tid >= d) ? lds[tid - d] : 0;
        __syncthreads();
        lds[tid] += t2;
        __syncthreads();
    }
    int excl = lds[tid] - s;
    if (tid == 255) bsum[blockIdx.x] = lds[255];
    int run = excl;
#pragma unroll
    for (int j = 0; j < 8; ++j) { int i = base + j; if (i < N) rowptr[i] = run; run += v[j]; }
}

__global__ void scanB(int* __restrict__ bsum, int nb, int* __restrict__ totalOut) {
    __shared__ int lds[128];
    int tid = threadIdx.x;
    int v = (tid < nb) ? bsum[tid] : 0;
    lds[tid] = v; __syncthreads();
    for (int d = 1; d < 128; d <<= 1) {
        int t2 = (tid >= d) ? lds[tid - d] : 0;
        __syncthreads();
        lds[tid] += t2;
        __syncthreads();
    }
    if (tid < nb) bsum[tid] = lds[tid] - v;
    if (tid == 127) *totalOut = lds[127];
}

__global__ void scanC(int* __restrict__ rowptr, const int* __restrict__ bsum, int N) {
    int i = blockIdx.x * 256 + threadIdx.x;
    if (i < N) rowptr[i] += bsum[i >> 11];
}

// ---------------------------------------------------------------- encoders (first linear+relu)
__global__ void enc(const float* __restrict__ ctrs, const float* __restrict__ feats,
                    const float* __restrict__ w_in1, const float* __restrict__ b_in1,
                    const float* __restrict__ w_seg1, const float* __restrict__ b_seg1,
                    unsigned short* __restrict__ h_in, unsigned short* __restrict__ h_seg, int N) {
    int idx = blockIdx.x * 256 + threadIdx.x;
    if (idx >= N * 128) return;
    int n = idx >> 7, c = idx & 127;
    float x0 = ctrs[2 * n], x1 = ctrs[2 * n + 1];
    float h = fmaxf(x0 * w_in1[c] + x1 * w_in1[128 + c] + b_in1[c], 0.f);
    h_in[idx] = f2bf(h);
    x0 = feats[2 * n]; x1 = feats[2 * n + 1];
    h = fmaxf(x0 * w_seg1[c] + x1 * w_seg1[128 + c] + b_seg1[c], 0.f);
    h_seg[idx] = f2bf(h);
}

// ---------------------------------------------------------------- GEMM (128-row tile, K=128)
// mfma(A=W^T frag, B=feat frag): lane's 4 acc regs = 4 consecutive output cols.
enum { MODE_X = 0, MODE_GN = 1, MODE_GNADD = 2 };

template <int MODE>
__global__ __launch_bounds__(256, 2) void gemm128(
    const unsigned short* __restrict__ A,   // [M][128] bf16
    const unsigned short* __restrict__ Bt,  // [nt][128][128] bf16, Bt[t][c][k]
    int nt, int M,
    unsigned short* __restrict__ Xout,      // MODE_X planes (minus plane0 if has0)
    unsigned short* __restrict__ X0out,     // MODE_X plane0 dest (tempb) if has0
    int has0,
    const unsigned short* __restrict__ resb,  // MODE_GNADD residual bf16
    float* __restrict__ outf,                 // MODE_GNADD optional f32 out
    unsigned short* __restrict__ outb,        // MODE_GN / MODE_GNADD bf16 out
    const float* __restrict__ gw, const float* __restrict__ gb) {
    __shared__ char Asm[32768];
    __shared__ char Bsm[32768];
    const int tid = threadIdx.x;
    const int wv = tid >> 6, ln = tid & 63;
    const int q = ln >> 4, r = ln & 15;
    const int m0 = blockIdx.x * 128;

    // stage A tile once: 128 rows x 16 int4 chunks, XOR-swizzled
#pragma unroll
    for (int s = 0; s < 8; ++s) {
        int f = s * 256 + tid;
        int row = f >> 4, ck = f & 15;
        int grow = m0 + row; if (grow >= M) grow = M - 1;
        int4 v = *(const int4*)(A + (size_t)grow * 128 + ck * 8);
        *(int4*)(Asm + row * 256 + ((ck * 16) ^ ((row & 7) << 4))) = v;
    }

    for (int t = 0; t < nt; ++t) {
        __syncthreads();
        const unsigned short* Bp = Bt + (size_t)t * 16384;
#pragma unroll
        for (int s = 0; s < 8; ++s) {
            int f = s * 256 + tid;
            int c = f >> 4, ck = f & 15;
            int4 v = *(const int4*)(Bp + c * 128 + ck * 8);
            *(int4*)(Bsm + c * 256 + ((ck * 16) ^ ((c & 7) << 4))) = v;
        }
        __syncthreads();

        f32x4 acc[2][8];
#pragma unroll
        for (int fj = 0; fj < 2; ++fj)
#pragma unroll
            for (int ci = 0; ci < 8; ++ci) acc[fj][ci] = (f32x4)(0.f);

#pragma unroll
        for (int k0 = 0; k0 < 128; k0 += 32) {
            int kb = k0 * 2 + q * 16;
            bf16x8 wf[8], ff[2];
#pragma unroll
            for (int ci = 0; ci < 8; ++ci) {
                int c = ci * 16 + r;
                wf[ci] = *(const bf16x8*)(Bsm + c * 256 + (kb ^ ((c & 7) << 4)));
            }
#pragma unroll
            for (int fj = 0; fj < 2; ++fj) {
                int row = wv * 32 + fj * 16 + r;
                ff[fj] = *(const bf16x8*)(Asm + row * 256 + (kb ^ ((row & 7) << 4)));
            }
#pragma unroll
            for (int fj = 0; fj < 2; ++fj)
#pragma unroll
                for (int ci = 0; ci < 8; ++ci)
                    acc[fj][ci] = __builtin_amdgcn_mfma_f32_16x16x32_bf16(wf[ci], ff[fj], acc[fj][ci], 0, 0, 0);
        }

        if (MODE == MODE_X) {
            unsigned short* dstp;
            if (has0 && t == 0) dstp = X0out;
            else dstp = Xout + (size_t)(t - has0) * (size_t)M * 128;
#pragma unroll
            for (int fj = 0; fj < 2; ++fj) {
                int row = m0 + wv * 32 + fj * 16 + r;
                if (row < M) {
                    unsigned short* dst = dstp + (size_t)row * 128;
#pragma unroll
                    for (int ci = 0; ci < 8; ++ci) {
                        int col = ci * 16 + q * 4;
                        f32x4 a = acc[fj][ci];
                        unsigned lo = (unsigned)f2bf(a[0]) | ((unsigned)f2bf(a[1]) << 16);
                        unsigned hi = (unsigned)f2bf(a[2]) | ((unsigned)f2bf(a[3]) << 16);
                        int2 pk; pk.x = (int)lo; pk.y = (int)hi;
                        *(int2*)(dst + col) = pk;
                    }
                }
            }
        } else {
#pragma unroll
            for (int fj = 0; fj < 2; ++fj) {
                float s = 0.f;
#pragma unroll
                for (int ci = 0; ci < 8; ++ci) {
                    f32x4 a = acc[fj][ci];
                    s += a[0] + a[1] + a[2] + a[3];
                }
                s += __shfl_xor(s, 16); s += __shfl_xor(s, 32);
                float mean = s * (1.f / 128.f);
                float vs = 0.f;
#pragma unroll
                for (int ci = 0; ci < 8; ++ci) {
                    f32x4 a = acc[fj][ci];
#pragma unroll
                    for (int j = 0; j < 4; ++j) { float d = a[j] - mean; vs += d * d; }
                }
                vs += __shfl_xor(vs, 16); vs += __shfl_xor(vs, 32);
                float inv = rsqrtf(vs * (1.f / 128.f) + 1e-5f);
                int row = m0 + wv * 32 + fj * 16 + r;
                if (row < M) {
#pragma unroll
                    for (int ci = 0; ci < 8; ++ci) {
                        int col = ci * 16 + q * 4;
                        f32x4 a = acc[fj][ci];
                        float4 gv = *(const float4*)(gw + col);
                        float4 bv = *(const float4*)(gb + col);
                        float y0 = (a[0] - mean) * inv * gv.x + bv.x;
                        float y1 = (a[1] - mean) * inv * gv.y + bv.y;
                        float y2 = (a[2] - mean) * inv * gv.z + bv.z;
                        float y3 = (a[3] - mean) * inv * gv.w + bv.w;
                        if (MODE == MODE_GNADD) {
                            int2 rv = *(const int2*)(resb + (size_t)row * 128 + col);
                            y0 = fmaxf(y0 + bfl((unsigned)rv.x), 0.f);
                            y1 = fmaxf(y1 + bfh((unsigned)rv.x), 0.f);
                            y2 = fmaxf(y2 + bfl((unsigned)rv.y), 0.f);
                            y3 = fmaxf(y3 + bfh((unsigned)rv.y), 0.f);
                            if (outf) {
                                float4 o; o.x = y0; o.y = y1; o.z = y2; o.w = y3;
                                *(float4*)(outf + (size_t)row * 128 + col) = o;
                            }
                        }
                        unsigned lo = (unsigned)f2bf(y0) | ((unsigned)f2bf(y1) << 16);
                        unsigned hi = (unsigned)f2bf(y2) | ((unsigned)f2bf(y3) << 16);
                        int2 pk; pk.x = (int)lo; pk.y = (int)hi;
                        *(int2*)(outb + (size_t)row * 128 + col) = pk;
                    }
                }
            }
        }
    }
}

// ---------------------------------------------------------------- gather (+GN+ReLU on LAST)
// One wave per node. Lane-parallel edge prefetch + 4 row-loads in flight with
// 4 independent accumulator pairs. temp held bf16-packed (1 word/lane).
template <int LAST>
__global__ __launch_bounds__(256) void gather2(
    const unsigned* __restrict__ Xu, int Nn,
    const int* __restrict__ rowptr, const int* __restrict__ edata,
    unsigned* __restrict__ tempb, unsigned* __restrict__ outw,
    const float* __restrict__ gw, const float* __restrict__ gb) {
    const int ln = threadIdx.x & 63;
    const int u = blockIdx.x * 4 + (threadIdx.x >> 6);
    if (u >= Nn) return;
    const int e0 = rowptr[u];
    const int deg = rowptr[u + 1] - e0;
    if (!LAST && deg == 0) return;  // temp row unchanged
    const unsigned uw = (unsigned)u * 64u + (unsigned)ln;
    unsigned tp = tempb[uw];
    float a0 = bfl(tp), a1 = bfh(tp);
    float b0 = 0.f, b1 = 0.f, c0 = 0.f, c1 = 0.f, e0f = 0.f, e1f = 0.f;
    const unsigned pstride = (unsigned)Nn * 64u;
    for (int base = 0; base < deg; base += 64) {
        int cnt = deg - base; if (cnt > 64) cnt = 64;
        int my = (ln < cnt) ? edata[e0 + base + ln] : 0;
        for (int j = 0; j < cnt; j += 4) {
            int w0 = __shfl(my, j);
            int w1 = __shfl(my, j + 1);
            int w2 = __shfl(my, j + 2);
            int w3 = __shfl(my, j + 3);
            unsigned p0 = Xu[(unsigned)(w0 >> 18) * pstride + (unsigned)(w0 & 0x3FFFF) * 64u + ln];
            unsigned p1 = Xu[(unsigned)(w1 >> 18) * pstride + (unsigned)(w1 & 0x3FFFF) * 64u + ln];
            unsigned p2 = Xu[(unsigned)(w2 >> 18) * pstride + (unsigned)(w2 & 0x3FFFF) * 64u + ln];
            unsigned p3 = Xu[(unsigned)(w3 >> 18) * pstride + (unsigned)(w3 & 0x3FFFF) * 64u + ln];
            a0 += bfl(p0); a1 += bfh(p0);
            if (j + 1 < cnt) { b0 += bfl(p1); b1 += bfh(p1); }
            if (j + 2 < cnt) { c0 += bfl(p2); c1 += bfh(p2); }
            if (j + 3 < cnt) { e0f += bfl(p3); e1f += bfh(p3); }
        }
    }
    a0 = (a0 + b0) + (c0 + e0f);
    a1 = (a1 + b1) + (c1 + e1f);
    if (LAST) {
        float s = a0 + a1;
#pragma unroll
        for (int d = 1; d < 64; d <<= 1) s += __shfl_xor(s, d);
        float mean = s * (1.f / 128.f);
        float d0 = a0 - mean, d1 = a1 - mean;
        float vs = d0 * d0 + d1 * d1;
#pragma unroll
        for (int d = 1; d < 64; d <<= 1) vs += __shfl_xor(vs, d);
        float inv = rsqrtf(vs * (1.f / 128.f) + 1e-5f);
        int c = ln * 2;
        float y0 = fmaxf(d0 * inv * gw[c] + gb[c], 0.f);
        float y1 = fmaxf(d1 * inv * gw[c + 1] + gb[c + 1], 0.f);
        outw[uw] = (unsigned)f2bf(y0) | ((unsigned)f2bf(y1) << 16);
    } else {
        tempb[uw] = (unsigned)f2bf(a0) | ((unsigned)f2bf(a1) << 16);
    }
}

// ---------------------------------------------------------------- launch
extern "C" void kernel_launch(void* const* d_in, const int* in_sizes, int n_in,
                              void* d_out, int out_size, void* d_ws, size_t ws_size,
                              hipStream_t stream) {
    const float* ctrs = (const float*)d_in[0];
    const float* feats = (const float*)d_in[1];
    const float* w_in1 = (const float*)d_in[2];
    const float* b_in1 = (const float*)d_in[3];
    const float* w_in2 = (const float*)d_in[4];
    const float* g_in = (const float*)d_in[5];
    const float* be_in = (const float*)d_in[6];
    const float* w_seg1 = (const float*)d_in[7];
    const float* b_seg1 = (const float*)d_in[8];
    const float* w_seg2 = (const float*)d_in[9];
    const float* g_seg = (const float*)d_in[10];
    const float* be_seg = (const float*)d_in[11];
    const float* ctr_w = (const float*)d_in[12];
    const float* pre_w = (const float*)d_in[13];
    const float* suc_w = (const float*)d_in[14];
    const float* left_w = (const float*)d_in[15];
    const float* right_w = (const float*)d_in[16];
    const float* norm_g = (const float*)d_in[17];
    const float* norm_b = (const float*)d_in[18];
    const float* ctr2_w = (const float*)d_in[19];
    const float* ctr2_g = (const float*)d_in[20];
    const float* ctr2_b = (const float*)d_in[21];
    const int* pre_u = (const int*)d_in[22];
    const int* pre_v = (const int*)d_in[23];
    const int* suc_u = (const int*)d_in[24];
    const int* suc_v = (const int*)d_in[25];
    const int* left_u = (const int*)d_in[26];
    const int* left_v = (const int*)d_in[27];
    const int* right_u = (const int*)d_in[28];
    const int* right_v = (const int*)d_in[29];

    const int N = in_sizes[0] / 2;
    const int E = in_sizes[22] / 6;
    const int E2 = in_sizes[26];
    const int Mtot = 12 * E + 2 * E2;

    char* ws = (char*)d_ws;
    size_t off = 0;
    auto alloc = [&](size_t b) { void* p = ws + off; off += (b + 255) & ~(size_t)255; return p; };

    unsigned short* Btw = (unsigned short*)alloc((size_t)66 * 16384 * 2);
    unsigned short* featb = (unsigned short*)alloc((size_t)N * 128 * 2);
    unsigned short* feat1b = (unsigned short*)alloc((size_t)N * 128 * 2);
    unsigned short* tempb = (unsigned short*)alloc((size_t)N * 128 * 2);
    int* rowptrs = (int*)alloc((size_t)14 * (N + 1) * 4);
    int* cnt = (int*)alloc((size_t)N * 4);
    int* bsum = (int*)alloc(1024);
    int* edata = (int*)alloc((size_t)Mtot * 4);
    size_t planeB = (size_t)N * 128 * 2;
    size_t rem = ws_size > off ? ws_size - off : 0;
    int navail = (int)(rem / planeB);
    if (navail > 14) navail = 14;
    if (navail < 1) navail = 1;
    unsigned short* X = (unsigned short*)(ws + off);

    float* featf = (float*)d_out;
    unsigned* tempw = (unsigned*)tempb;
    unsigned* feat1w = (unsigned*)feat1b;
    const unsigned* Xw = (const unsigned*)X;

    // type groups over edge types 1..14
    int G = (14 + navail - 1) / navail;
    int t0s[14], t1s[14]; size_t eoffs[14];
    {
        int per = 14 / G, extra = 14 % G, tcur = 1; size_t ecur = 0;
        for (int g = 0; g < G; ++g) {
            int sz = per + (g < extra ? 1 : 0);
            t0s[g] = tcur; t1s[g] = tcur + sz; eoffs[g] = ecur;
            for (int t = tcur; t < tcur + sz; ++t) ecur += (t <= 12) ? (size_t)E : (size_t)E2;
            tcur += sz;
        }
    }

    wprep<<<dim3((66 * 16384 + 255) / 256), dim3(256), 0, stream>>>(
        w_in2, w_seg2, ctr_w, pre_w, suc_w, left_w, right_w, ctr2_w, Btw);

    // per-group CSR build
    int nb = (N + 2047) / 2048;
    dim3 eg((Mtot + 255) / 256);
    for (int g = 0; g < G; ++g) {
        int* rp = rowptrs + (size_t)g * (N + 1);
        int* ed = edata + eoffs[g];
        hipMemsetAsync(cnt, 0, (size_t)N * 4, stream);
        edge_count_r<<<eg, dim3(256), 0, stream>>>(
            pre_u, pre_v, suc_u, suc_v, left_u, left_v, right_u, right_v,
            E, E2, Mtot, t0s[g], t1s[g], cnt);
        scanA<<<dim3(nb), dim3(256), 0, stream>>>(cnt, N, rp, bsum);
        scanB<<<dim3(1), dim3(128), 0, stream>>>(bsum, nb, rp + N);
        scanC<<<dim3((N + 255) / 256), dim3(256), 0, stream>>>(rp, bsum, N);
        hipMemsetAsync(cnt, 0, (size_t)N * 4, stream);
        edge_fill_r<<<eg, dim3(256), 0, stream>>>(
            pre_u, pre_v, suc_u, suc_v, left_u, left_v, right_u, right_v,
            E, E2, Mtot, t0s[g], t1s[g], rp, cnt, ed);
    }

    // encoders
    enc<<<dim3((N * 128 + 255) / 256), dim3(256), 0, stream>>>(
        ctrs, feats, w_in1, b_in1, w_seg1, b_seg1, feat1b, featb, N);
    const int gblk = (N + 127) / 128;
    gemm128<MODE_GN><<<dim3(gblk), dim3(256), 0, stream>>>(
        feat1b, Btw, 1, N, nullptr, nullptr, 0, nullptr, nullptr, feat1b, g_in, be_in);
    gemm128<MODE_GNADD><<<dim3(gblk), dim3(256), 0, stream>>>(
        featb, Btw + 16384, 1, N, nullptr, nullptr, 0, feat1b, nullptr, featb, g_seg, be_seg);

    // fuse iterations
    for (int i = 0; i < 4; ++i) {
        for (int g = 0; g < G; ++g) {
            int has0 = (g == 0) ? 1 : 0;
            int nt = (t1s[g] - t0s[g]) + has0;
            const unsigned short* Bp = Btw + (size_t)(2 + i * 15 + (has0 ? 0 : t0s[g])) * 16384;
            gemm128<MODE_X><<<dim3(gblk), dim3(256), 0, stream>>>(
                featb, Bp, nt, N, X, tempb, has0, nullptr, nullptr, nullptr, nullptr, nullptr);
            const int* rp = rowptrs + (size_t)g * (N + 1);
            const int* ed = edata + eoffs[g];
            dim3 ggrid((N + 3) / 4);
            if (g == G - 1)
                gather2<1><<<ggrid, dim3(256), 0, stream>>>(
                    Xw, N, rp, ed, tempw, feat1w, norm_g + i * 128, norm_b + i * 128);
            else
                gather2<0><<<ggrid, dim3(256), 0, stream>>>(
                    Xw, N, rp, ed, tempw, nullptr, nullptr, nullptr);
        }
        gemm128<MODE_GNADD><<<dim3(gblk), dim3(256), 0, stream>>>(
            feat1b, Btw + (size_t)(62 + i) * 16384, 1, N, nullptr, nullptr, 0,
            featb, (i == 3) ? featf : nullptr, featb, ctr2_g + i * 128, ctr2_b + i * 128);
    }
}